// Round 1
// baseline (15408.832 us; speedup 1.0000x reference)
//
#include <hip/hip_runtime.h>
#include <hip/hip_bf16.h>
#include <math.h>

// Problem constants
#define HID 4096      // H*O
#define NMAX 2048
#define EMAX 16384
#define RREL 4

// ---------- helpers ----------
__device__ __forceinline__ unsigned fenc(float f) {
  unsigned u = __float_as_uint(f);
  return (u & 0x80000000u) ? ~u : (u | 0x80000000u);
}
__device__ __forceinline__ float fdec(unsigned u) {
  return (u & 0x80000000u) ? __uint_as_float(u & 0x7fffffffu) : __uint_as_float(~u);
}

// ---------- GEMM: C[M,N] = A[M,K] @ B[K,N] (+C if accum), all row-major fp32 ----------
// 128x128 block tile, BK=8, 256 threads, 8x8 per thread.
__global__ __launch_bounds__(256) void gemm128(const float* __restrict__ A,
                                               const float* __restrict__ B,
                                               float* __restrict__ C,
                                               int M, int N, int K, int accum) {
  __shared__ float As[8][132];  // [k][m], padded so float4 reads stay 16B aligned
  __shared__ float Bs[8][132];  // [k][n]
  int t = threadIdx.x;
  int tx = t & 15, ty = t >> 4;
  int row0 = blockIdx.y * 128, col0 = blockIdx.x * 128;
  float acc[2][2][4][4] = {};
  int am = t >> 1, ak = (t & 1) << 2;   // A tile: 128 rows x 8 k, float4 per thread
  int bk = t >> 5, bn = (t & 31) << 2;  // B tile: 8 k x 128 cols, float4 per thread
  const float* Ap = A + (size_t)(row0 + am) * K + ak;
  const float* Bp = B + (size_t)bk * N + col0 + bn;
  for (int kb = 0; kb < K; kb += 8) {
    float4 av = *(const float4*)(Ap + kb);
    float4 bv = *(const float4*)(Bp + (size_t)kb * N);
    As[ak + 0][am] = av.x;
    As[ak + 1][am] = av.y;
    As[ak + 2][am] = av.z;
    As[ak + 3][am] = av.w;
    *(float4*)&Bs[bk][bn] = bv;
    __syncthreads();
#pragma unroll
    for (int kk = 0; kk < 8; kk++) {
      float4 a0 = *(const float4*)&As[kk][ty * 4];
      float4 a1 = *(const float4*)&As[kk][64 + ty * 4];
      float4 b0 = *(const float4*)&Bs[kk][tx * 4];
      float4 b1 = *(const float4*)&Bs[kk][64 + tx * 4];
      float ar[2][4] = {{a0.x, a0.y, a0.z, a0.w}, {a1.x, a1.y, a1.z, a1.w}};
      float br[2][4] = {{b0.x, b0.y, b0.z, b0.w}, {b1.x, b1.y, b1.z, b1.w}};
#pragma unroll
      for (int gi = 0; gi < 2; gi++)
#pragma unroll
        for (int i = 0; i < 4; i++)
#pragma unroll
          for (int gj = 0; gj < 2; gj++)
#pragma unroll
            for (int jj = 0; jj < 4; jj++)
              acc[gi][gj][i][jj] += ar[gi][i] * br[gj][jj];
    }
    __syncthreads();
  }
#pragma unroll
  for (int gi = 0; gi < 2; gi++)
#pragma unroll
    for (int i = 0; i < 4; i++) {
      int row = row0 + gi * 64 + ty * 4 + i;
#pragma unroll
      for (int gj = 0; gj < 2; gj++) {
        int col = col0 + gj * 64 + tx * 4;
        float* cp = C + (size_t)row * N + col;
        float4 v = {acc[gi][gj][i][0], acc[gi][gj][i][1], acc[gi][gj][i][2],
                    acc[gi][gj][i][3]};
        if (accum) {
          float4 o = *(const float4*)cp;
          v.x += o.x; v.y += o.y; v.z += o.z; v.w += o.w;
        }
        *(float4*)cp = v;
      }
    }
}

// ---------- el/er: per node, el[n,h] = sum_o feat[n,h*1024+o]*al[h*1024+o] ----------
__global__ __launch_bounds__(256) void el_er_k(const float* __restrict__ feat,
                                               const float* __restrict__ al,
                                               const float* __restrict__ ar,
                                               float* __restrict__ el,
                                               float* __restrict__ er) {
  int n = blockIdx.x;
  int t = threadIdx.x;
  const float* row = feat + (size_t)n * HID;
  float pel[4] = {}, per_[4] = {};
#pragma unroll
  for (int it = 0; it < 16; it++) {
    int idx = it * 256 + t;
    float f = row[idx];
    const int h = it >> 2;  // compile-time per unrolled it
    pel[h] += f * al[idx];
    per_[h] += f * ar[idx];
  }
  __shared__ float red[256][9];
#pragma unroll
  for (int h = 0; h < 4; h++) { red[t][h] = pel[h]; red[t][4 + h] = per_[h]; }
  __syncthreads();
  for (int s = 128; s > 0; s >>= 1) {
    if (t < s)
#pragma unroll
      for (int j = 0; j < 8; j++) red[t][j] += red[t + s][j];
    __syncthreads();
  }
  if (t < 4) { el[n * 4 + t] = red[0][t]; er[n * 4 + t] = red[0][4 + t]; }
}

// ---------- CSR build ----------
__global__ void count_k(const int* __restrict__ dst, int* __restrict__ counts, int E) {
  int i = blockIdx.x * blockDim.x + threadIdx.x;
  if (i < E) atomicAdd(&counts[dst[i]], 1);
}

__global__ __launch_bounds__(256) void scan_k(const int* __restrict__ counts,
                                              int* __restrict__ row_ptr, int N) {
  __shared__ int sums[256];
  int t = threadIdx.x;
  int per = (N + 255) / 256;  // <= 8
  int local[8];
  int base = t * per;
  int s = 0;
  for (int i = 0; i < per; i++) {
    int idx = base + i;
    int v = (idx < N) ? counts[idx] : 0;
    s += v;
    local[i] = s;  // inclusive within thread
  }
  sums[t] = s;
  __syncthreads();
  for (int off = 1; off < 256; off <<= 1) {
    int v = (t >= off) ? sums[t - off] : 0;
    __syncthreads();
    sums[t] += v;
    __syncthreads();
  }
  int offset = (t > 0) ? sums[t - 1] : 0;
  for (int i = 0; i < per; i++) {
    int idx = base + i;
    if (idx < N) row_ptr[idx + 1] = offset + local[i];
  }
  if (t == 0) row_ptr[0] = 0;
}

__global__ void scatter_k(const int* __restrict__ dst, int* __restrict__ cnt,
                          const int* __restrict__ row_ptr, int* __restrict__ edge_ord,
                          int E) {
  int i = blockIdx.x * blockDim.x + threadIdx.x;
  if (i < E) {
    int d = dst[i];
    int off = atomicAdd(&cnt[d], 1);
    edge_ord[row_ptr[d] + off] = i;
  }
}

// ---------- edge softmax ----------
__global__ void edge_vals_k(const int* __restrict__ src, const int* __restrict__ dst,
                            const float* __restrict__ el, const float* __restrict__ er,
                            float* __restrict__ ev, int E4) {
  int i = blockIdx.x * blockDim.x + threadIdx.x;
  if (i >= E4) return;
  int e = i >> 2, h = i & 3;
  float v = el[src[e] * 4 + h] + er[dst[e] * 4 + h];
  ev[i] = v > 0.f ? v : 0.2f * v;  // leaky_relu 0.2
}

__global__ void edge_max_k(const int* __restrict__ dst, const float* __restrict__ ev,
                           unsigned* __restrict__ mkey, int E4) {
  int i = blockIdx.x * blockDim.x + threadIdx.x;
  if (i >= E4) return;
  atomicMax(&mkey[dst[i >> 2] * 4 + (i & 3)], fenc(ev[i]));
}

__global__ void edge_p_k(const int* __restrict__ dst, const float* __restrict__ ev,
                         const unsigned* __restrict__ mkey, float* __restrict__ p,
                         float* __restrict__ s, int E4) {
  int i = blockIdx.x * blockDim.x + threadIdx.x;
  if (i >= E4) return;
  int d4 = dst[i >> 2] * 4 + (i & 3);
  float m = fdec(mkey[d4]);
  float pv = expf(ev[i] - m);
  p[i] = pv;
  atomicAdd(&s[d4], pv);
}

__global__ void edge_alpha_k(const int* __restrict__ dst, const float* __restrict__ s,
                             float* __restrict__ p, int E4) {
  int i = blockIdx.x * blockDim.x + threadIdx.x;
  if (i >= E4) return;
  float sv = s[dst[i >> 2] * 4 + (i & 3)];
  p[i] = p[i] / (sv > 0.f ? sv : 1.f);
}

// ---------- aggregation: acc[dst] += sum_e alpha[e,h]*feat[src_e, h*1024+o] ----------
__global__ __launch_bounds__(256) void agg_k(const float* __restrict__ feat,
                                             const float* __restrict__ alpha,
                                             const int* __restrict__ row_ptr,
                                             const int* __restrict__ edge_ord,
                                             const int* __restrict__ src,
                                             float* __restrict__ acc) {
  int n = blockIdx.x;
  int start = row_ptr[n], end = row_ptr[n + 1];
  if (end == start) return;
  __shared__ int s_src[256];
  __shared__ float s_al[256][4];
  int t = threadIdx.x;
  float out[16] = {};
  for (int c = start; c < end; c += 256) {
    int m = min(256, end - c);
    if (t < m) {
      int eid = edge_ord[c + t];
      s_src[t] = src[eid];
#pragma unroll
      for (int h = 0; h < 4; h++) s_al[t][h] = alpha[eid * 4 + h];
    }
    __syncthreads();
    for (int i = 0; i < m; i++) {
      const float* frow = feat + (size_t)s_src[i] * HID;
      float a0 = s_al[i][0], a1 = s_al[i][1], a2 = s_al[i][2], a3 = s_al[i][3];
#pragma unroll
      for (int j = 0; j < 16; j++) {
        int idx = j * 256 + t;  // head = j>>2
        float av = (j < 4) ? a0 : (j < 8) ? a1 : (j < 12) ? a2 : a3;
        out[j] += av * frow[idx];
      }
    }
    __syncthreads();
  }
#pragma unroll
  for (int j = 0; j < 16; j++) acc[(size_t)n * HID + j * 256 + t] += out[j];
}

// ---------- finalize layer1: h = elu((acc + sum_r b1)/4) ----------
__global__ __launch_bounds__(256) void finalize1_k(const float* __restrict__ acc,
                                                   const float* __restrict__ b1,
                                                   float* __restrict__ h, int total) {
  int i = blockIdx.x * 256 + threadIdx.x;
  if (i >= total) return;
  int col = i & (HID - 1);
  float bs = b1[col] + b1[HID + col] + b1[2 * HID + col] + b1[3 * HID + col];
  float v = (acc[i] + bs) * 0.25f;
  h[i] = v > 0.f ? v : (expf(v) - 1.f);
}

// ---------- finalize layer2 + column mean into gm ----------
__global__ __launch_bounds__(256) void finalize2_mean_k(const float* __restrict__ acc,
                                                        const float* __restrict__ h,
                                                        const float* __restrict__ b2,
                                                        float* __restrict__ gm, int Nn,
                                                        float invN) {
  int col = blockIdx.x * 256 + threadIdx.x;
  int r0 = blockIdx.y * 32;
  int r1 = min(r0 + 32, Nn);
  float bs = 0.25f * (b2[col] + b2[HID + col] + b2[2 * HID + col] + b2[3 * HID + col]);
  float p = 0.f;
  for (int r = r0; r < r1; r++) {
    size_t i = (size_t)r * HID + col;
    p += acc[i] * 0.25f + h[i] + bs;
  }
  atomicAdd(&gm[col], p * invN);
}

// ---------- readout MLP ----------
__global__ void initvec_k(float* __restrict__ out, const float* __restrict__ b, int n) {
  int i = blockIdx.x * blockDim.x + threadIdx.x;
  if (i < n) out[i] = b[i];
}

__global__ __launch_bounds__(256) void matvec_k(const float* __restrict__ v,
                                                const float* __restrict__ W,
                                                float* __restrict__ out, int K, int Nout,
                                                int kchunk) {
  int j = blockIdx.x * 256 + threadIdx.x;
  if (j >= Nout) return;
  int k0 = blockIdx.y * kchunk;
  int k1 = min(k0 + kchunk, K);
  float p = 0.f;
  for (int k = k0; k < k1; k++) p += v[k] * W[(size_t)k * Nout + j];
  atomicAdd(&out[j], p);
}

__global__ __launch_bounds__(256) void final_k(const float* __restrict__ hc,
                                               const float* __restrict__ Wc2,
                                               const float* __restrict__ bc2,
                                               float* __restrict__ out) {
  __shared__ float red[256];
  int t = threadIdx.x;
  for (int c = 0; c < 3; c++) {
    float p = 0.f;
    for (int k = t; k < 1024; k += 256) {
      float v = hc[k];
      v = v > 0.f ? v : 0.f;  // relu
      p += v * Wc2[k * 3 + c];
    }
    red[t] = p;
    __syncthreads();
    for (int s = 128; s > 0; s >>= 1) {
      if (t < s) red[t] += red[t + s];
      __syncthreads();
    }
    if (t == 0) out[c] = red[0] + bc2[c];
    __syncthreads();
  }
}

// ================= host side =================
extern "C" void kernel_launch(void* const* d_in, const int* in_sizes, int n_in,
                              void* d_out, int out_size, void* d_ws, size_t ws_size,
                              hipStream_t stream) {
  const float* x_pre = (const float*)d_in[0];
  const float* x_hyp = (const float*)d_in[1];
  const float* x_comb = (const float*)d_in[2];
  const int* src_pre = (const int*)d_in[3];
  const int* dst_pre = (const int*)d_in[4];
  const int* src_hyp = (const int*)d_in[5];
  const int* dst_hyp = (const int*)d_in[6];
  const int* src_comb = (const int*)d_in[7];
  const int* dst_comb = (const int*)d_in[8];
  const float* W1 = (const float*)d_in[9];
  const float* al1 = (const float*)d_in[10];
  const float* ar1 = (const float*)d_in[11];
  const float* b1 = (const float*)d_in[12];
  const float* res1 = (const float*)d_in[13];
  const float* W2 = (const float*)d_in[14];
  const float* al2 = (const float*)d_in[15];
  const float* ar2 = (const float*)d_in[16];
  const float* b2 = (const float*)d_in[17];
  const float* Wp = (const float*)d_in[18];
  const float* bp = (const float*)d_in[19];
  const float* Wc1 = (const float*)d_in[20];
  const float* bc1 = (const float*)d_in[21];
  const float* Wc2 = (const float*)d_in[22];
  const float* bc2 = (const float*)d_in[23];
  float* out = (float*)d_out;

  // workspace carve-up (256B aligned)
  char* w = (char*)d_ws;
  size_t off = 0;
  auto alloc = [&](size_t bytes) -> void* {
    void* p = w + off;
    off = (off + bytes + 255) & ~(size_t)255;
    return p;
  };
  float* h = (float*)alloc((size_t)NMAX * HID * 4);
  float* acc = (float*)alloc((size_t)NMAX * HID * 4);
  float* feat = (float*)alloc((size_t)NMAX * HID * 4);
  float* el = (float*)alloc(NMAX * 4 * 4);
  float* er = (float*)alloc(NMAX * 4 * 4);
  float* evals = (float*)alloc(EMAX * 4 * 4);
  float* alpha = (float*)alloc(EMAX * 4 * 4);
  unsigned* mkey = (unsigned*)alloc(NMAX * 4 * 4);
  float* sbuf = (float*)alloc(NMAX * 4 * 4);
  int* row_ptr = (int*)alloc(RREL * (NMAX + 1) * 4);
  int* edge_ord = (int*)alloc(RREL * EMAX * 4);
  int* counts = (int*)alloc(NMAX * 4);
  float* gm = (float*)alloc(3 * HID * 4);  // concatenated graph means (12288)
  float* z = (float*)alloc(3072 * 4);
  float* hc = (float*)alloc(1024 * 4);

  hipMemsetAsync(gm, 0, 3 * HID * 4, stream);

  struct GDesc { const float* x; const int* src; const int* dst; int N; int E; };
  GDesc gs[3] = {{x_pre, src_pre, dst_pre, 1024, 8192},
                 {x_hyp, src_hyp, dst_hyp, 1024, 8192},
                 {x_comb, src_comb, dst_comb, 2048, 16384}};

  for (int g = 0; g < 3; g++) {
    const float* x = gs[g].x;
    int N = gs[g].N, E = gs[g].E;
    int E4 = E * 4;
    dim3 gemmGrid(HID / 128, N / 128);
    int eb = (E + 255) / 256;
    int eb4 = (E4 + 255) / 256;

    // ---- CSR per relation (shared by both layers) ----
    for (int r = 0; r < RREL; r++) {
      const int* dstR = gs[g].dst + (size_t)r * E;
      int* rpR = row_ptr + r * (NMAX + 1);
      int* eoR = edge_ord + r * EMAX;
      hipMemsetAsync(counts, 0, N * 4, stream);
      count_k<<<eb, 256, 0, stream>>>(dstR, counts, E);
      scan_k<<<1, 256, 0, stream>>>(counts, rpR, N);
      hipMemsetAsync(counts, 0, N * 4, stream);
      scatter_k<<<eb, 256, 0, stream>>>(dstR, counts, rpR, eoR, E);
    }

    for (int layer = 0; layer < 2; layer++) {
      const float* xin = (layer == 0) ? x : h;
      int K = (layer == 0) ? 1024 : HID;
      const float* Wl = (layer == 0) ? W1 : W2;
      const float* all = (layer == 0) ? al1 : al2;
      const float* arl = (layer == 0) ? ar1 : ar2;
      hipMemsetAsync(acc, 0, (size_t)N * HID * 4, stream);
      for (int r = 0; r < RREL; r++) {
        const int* srcR = gs[g].src + (size_t)r * E;
        const int* dstR = gs[g].dst + (size_t)r * E;
        const int* rpR = row_ptr + r * (NMAX + 1);
        const int* eoR = edge_ord + r * EMAX;
        gemm128<<<gemmGrid, 256, 0, stream>>>(xin, Wl + (size_t)r * K * HID, feat, N,
                                              HID, K, 0);
        if (layer == 0)
          gemm128<<<gemmGrid, 256, 0, stream>>>(x, res1 + (size_t)r * 1024 * HID, acc,
                                                N, HID, 1024, 1);
        el_er_k<<<N, 256, 0, stream>>>(feat, all + r * HID, arl + r * HID, el, er);
        edge_vals_k<<<eb4, 256, 0, stream>>>(srcR, dstR, el, er, evals, E4);
        hipMemsetAsync(mkey, 0, N * 4 * 4, stream);
        edge_max_k<<<eb4, 256, 0, stream>>>(dstR, evals, mkey, E4);
        hipMemsetAsync(sbuf, 0, N * 4 * 4, stream);
        edge_p_k<<<eb4, 256, 0, stream>>>(dstR, evals, mkey, alpha, sbuf, E4);
        edge_alpha_k<<<eb4, 256, 0, stream>>>(dstR, sbuf, alpha, E4);
        agg_k<<<N, 256, 0, stream>>>(feat, alpha, rpR, eoR, srcR, acc);
      }
      if (layer == 0) {
        finalize1_k<<<N * (HID / 256), 256, 0, stream>>>(acc, b1, h, N * HID);
      } else {
        dim3 fg(HID / 256, (N + 31) / 32);
        finalize2_mean_k<<<fg, 256, 0, stream>>>(acc, h, b2, gm + g * HID, N,
                                                 1.0f / N);
      }
    }
  }

  // ---- readout MLP ----
  initvec_k<<<12, 256, 0, stream>>>(z, bp, 3072);
  {
    dim3 mg(3072 / 256, 48);  // K=12288 in chunks of 256
    matvec_k<<<mg, 256, 0, stream>>>(gm, Wp, z, 12288, 3072, 256);
  }
  initvec_k<<<4, 256, 0, stream>>>(hc, bc1, 1024);
  {
    dim3 mg(1024 / 256, 24);  // K=3072 in chunks of 128
    matvec_k<<<mg, 256, 0, stream>>>(z, Wc1, hc, 3072, 1024, 128);
  }
  final_k<<<1, 256, 0, stream>>>(hc, Wc2, bc2, out);
}

// Round 2
// 4421.140 us; speedup vs baseline: 3.4853x; 3.4853x over previous
//
#include <hip/hip_runtime.h>
#include <hip/hip_bf16.h>
#include <math.h>

#define HID 4096
#define NMAX 2048
#define EMAX 16384
#define RREL 4

typedef unsigned short ushortT;
typedef __attribute__((ext_vector_type(8))) short short8;
typedef __attribute__((ext_vector_type(4))) float floatx4;

// ---------- helpers ----------
__device__ __forceinline__ unsigned fenc(float f) {
  unsigned u = __float_as_uint(f);
  return (u & 0x80000000u) ? ~u : (u | 0x80000000u);
}
__device__ __forceinline__ float fdec(unsigned u) {
  return (u & 0x80000000u) ? __uint_as_float(u & 0x7fffffffu) : __uint_as_float(~u);
}
__device__ __forceinline__ ushortT f2b(float f) {  // fp32 -> bf16 RNE
  unsigned u = __float_as_uint(f);
  u = u + 0x7fffu + ((u >> 16) & 1u);
  return (ushortT)(u >> 16);
}
__device__ __forceinline__ float b2f_lo(unsigned u) { return __uint_as_float(u << 16); }
__device__ __forceinline__ float b2f_hi(unsigned u) { return __uint_as_float(u & 0xffff0000u); }
__device__ __forceinline__ float b2f1(ushortT u) { return __uint_as_float((unsigned)u << 16); }

// ---------- weight convert + transpose: W[K][4096] fp32 -> Wt[4096][K] bf16 ----------
__global__ __launch_bounds__(256) void convt_k(const float* __restrict__ W,
                                               ushortT* __restrict__ Wt, int K) {
  int bn = blockIdx.x * 32;  // column (n) tile of W
  int bk = blockIdx.y * 32;  // row (k) tile of W
  int t = threadIdx.x;
  __shared__ ushortT tile[32][40];  // [n][k]
  int kr = t >> 3;        // 0..31
  int nc = (t & 7) * 4;   // 0..28
  float4 v = *(const float4*)(W + (size_t)(bk + kr) * 4096 + bn + nc);
  tile[nc + 0][kr] = f2b(v.x);
  tile[nc + 1][kr] = f2b(v.y);
  tile[nc + 2][kr] = f2b(v.z);
  tile[nc + 3][kr] = f2b(v.w);
  __syncthreads();
  int n = t >> 3, j = (t & 7) * 4;
  uint2 u;
  u.x = (unsigned)tile[n][j] | ((unsigned)tile[n][j + 1] << 16);
  u.y = (unsigned)tile[n][j + 2] | ((unsigned)tile[n][j + 3] << 16);
  *(uint2*)(Wt + (size_t)(bn + n) * K + bk + j) = u;
}

// ---------- plain fp32 -> bf16 convert (row-major, n8 = elems/8) ----------
__global__ void f2b_k(const float* __restrict__ in, ushortT* __restrict__ out, int n8) {
  int i = blockIdx.x * 256 + threadIdx.x;
  if (i >= n8) return;
  const float4* p = (const float4*)in;
  float4 a = p[2 * i], b = p[2 * i + 1];
  uint4 u;
  u.x = (unsigned)f2b(a.x) | ((unsigned)f2b(a.y) << 16);
  u.y = (unsigned)f2b(a.z) | ((unsigned)f2b(a.w) << 16);
  u.z = (unsigned)f2b(b.x) | ((unsigned)f2b(b.y) << 16);
  u.w = (unsigned)f2b(b.z) | ((unsigned)f2b(b.w) << 16);
  *(uint4*)(out + 8 * i) = u;
}

// ---------- bf16 MFMA GEMM: C[M,4096] = A[M,K] @ Bt[4096,K]^T ----------
// mode 0: C=  (fp32)   1: C+= (fp32)   2: Cb= (bf16)
#define LDA 40
__global__ __launch_bounds__(256) void gemm_bt(const ushortT* __restrict__ A,
                                               const ushortT* __restrict__ Bt,
                                               float* __restrict__ C,
                                               ushortT* __restrict__ Cb,
                                               int M, int K, int mode) {
  __shared__ ushortT As[128 * LDA];
  __shared__ ushortT Bs[128 * LDA];
  int t = threadIdx.x;
  int row0 = blockIdx.y * 128, col0 = blockIdx.x * 128;
  int sm = t >> 2, sk = (t & 3) * 8;
  const ushortT* Ap0 = A + (size_t)(row0 + sm) * K + sk;
  const ushortT* Ap1 = A + (size_t)(row0 + sm + 64) * K + sk;
  const ushortT* Bp0 = Bt + (size_t)(col0 + sm) * K + sk;
  const ushortT* Bp1 = Bt + (size_t)(col0 + sm + 64) * K + sk;
  int wave = t >> 6, lane = t & 63;
  int wr = (wave & 1) * 64, wc = (wave >> 1) * 64;
  int lrow = lane & 15, lkg = lane >> 4;
  floatx4 acc[4][4];
#pragma unroll
  for (int r = 0; r < 4; r++)
#pragma unroll
    for (int c = 0; c < 4; c++) acc[r][c] = (floatx4){0.f, 0.f, 0.f, 0.f};

  for (int kb = 0; kb < K; kb += 32) {
    short8 va0 = *(const short8*)(Ap0 + kb);
    short8 va1 = *(const short8*)(Ap1 + kb);
    short8 vb0 = *(const short8*)(Bp0 + kb);
    short8 vb1 = *(const short8*)(Bp1 + kb);
    *(short8*)&As[sm * LDA + sk] = va0;
    *(short8*)&As[(sm + 64) * LDA + sk] = va1;
    *(short8*)&Bs[sm * LDA + sk] = vb0;
    *(short8*)&Bs[(sm + 64) * LDA + sk] = vb1;
    __syncthreads();
    short8 af[4], bf[4];
#pragma unroll
    for (int r = 0; r < 4; r++)
      af[r] = *(const short8*)&As[(wr + r * 16 + lrow) * LDA + lkg * 8];
#pragma unroll
    for (int c = 0; c < 4; c++)
      bf[c] = *(const short8*)&Bs[(wc + c * 16 + lrow) * LDA + lkg * 8];
#pragma unroll
    for (int r = 0; r < 4; r++)
#pragma unroll
      for (int c = 0; c < 4; c++)
        acc[r][c] = __builtin_amdgcn_mfma_f32_16x16x32_bf16(af[r], bf[c], acc[r][c], 0, 0, 0);
    __syncthreads();
  }
  // epilogue: C/D layout col=lane&15, row=(lane>>4)*4+reg
#pragma unroll
  for (int r = 0; r < 4; r++) {
    int row = row0 + wr + r * 16 + lkg * 4;
#pragma unroll
    for (int c = 0; c < 4; c++) {
      int col = col0 + wc + c * 16 + lrow;
#pragma unroll
      for (int j = 0; j < 4; j++) {
        size_t idx = (size_t)(row + j) * HID + col;
        if (mode == 0) C[idx] = acc[r][c][j];
        else if (mode == 1) C[idx] += acc[r][c][j];
        else Cb[idx] = f2b(acc[r][c][j]);
      }
    }
  }
}

// ---------- el/er from bf16 feat ----------
__global__ __launch_bounds__(256) void el_er_k(const ushortT* __restrict__ featb,
                                               const float* __restrict__ al,
                                               const float* __restrict__ ar,
                                               float* __restrict__ el,
                                               float* __restrict__ er) {
  int n = blockIdx.x, t = threadIdx.x;
  const unsigned* row = (const unsigned*)(featb + (size_t)n * HID);
  float pel[4] = {}, per_[4] = {};
#pragma unroll
  for (int j = 0; j < 8; j++) {
    unsigned u = row[j * 256 + t];
    int col = (j * 256 + t) * 2;
    const int h = j >> 1;
    pel[h] += b2f_lo(u) * al[col] + b2f_hi(u) * al[col + 1];
    per_[h] += b2f_lo(u) * ar[col] + b2f_hi(u) * ar[col + 1];
  }
  __shared__ float red[256][9];
#pragma unroll
  for (int h = 0; h < 4; h++) { red[t][h] = pel[h]; red[t][4 + h] = per_[h]; }
  __syncthreads();
  for (int s = 128; s > 0; s >>= 1) {
    if (t < s)
#pragma unroll
      for (int j = 0; j < 8; j++) red[t][j] += red[t + s][j];
    __syncthreads();
  }
  if (t < 4) { el[n * 4 + t] = red[0][t]; er[n * 4 + t] = red[0][4 + t]; }
}

// ---------- CSR build ----------
__global__ void count_k(const int* __restrict__ dst, int* __restrict__ counts, int E) {
  int i = blockIdx.x * blockDim.x + threadIdx.x;
  if (i < E) atomicAdd(&counts[dst[i]], 1);
}

__global__ __launch_bounds__(256) void scan_k(const int* __restrict__ counts,
                                              int* __restrict__ row_ptr, int N) {
  __shared__ int sums[256];
  int t = threadIdx.x;
  int per = (N + 255) / 256;
  int local[8];
  int base = t * per;
  int s = 0;
  for (int i = 0; i < per; i++) {
    int idx = base + i;
    int v = (idx < N) ? counts[idx] : 0;
    s += v;
    local[i] = s;
  }
  sums[t] = s;
  __syncthreads();
  for (int off = 1; off < 256; off <<= 1) {
    int v = (t >= off) ? sums[t - off] : 0;
    __syncthreads();
    sums[t] += v;
    __syncthreads();
  }
  int offset = (t > 0) ? sums[t - 1] : 0;
  for (int i = 0; i < per; i++) {
    int idx = base + i;
    if (idx < N) row_ptr[idx + 1] = offset + local[i];
  }
  if (t == 0) row_ptr[0] = 0;
}

__global__ void scatter_k(const int* __restrict__ dst, int* __restrict__ cnt,
                          const int* __restrict__ row_ptr, int* __restrict__ edge_ord,
                          int E) {
  int i = blockIdx.x * blockDim.x + threadIdx.x;
  if (i < E) {
    int d = dst[i];
    int off = atomicAdd(&cnt[d], 1);
    edge_ord[row_ptr[d] + off] = i;
  }
}

// ---------- edge softmax ----------
__global__ void edge_vals_k(const int* __restrict__ src, const int* __restrict__ dst,
                            const float* __restrict__ el, const float* __restrict__ er,
                            float* __restrict__ ev, int E4) {
  int i = blockIdx.x * blockDim.x + threadIdx.x;
  if (i >= E4) return;
  int e = i >> 2, h = i & 3;
  float v = el[src[e] * 4 + h] + er[dst[e] * 4 + h];
  ev[i] = v > 0.f ? v : 0.2f * v;
}

__global__ void edge_max_k(const int* __restrict__ dst, const float* __restrict__ ev,
                           unsigned* __restrict__ mkey, int E4) {
  int i = blockIdx.x * blockDim.x + threadIdx.x;
  if (i >= E4) return;
  atomicMax(&mkey[dst[i >> 2] * 4 + (i & 3)], fenc(ev[i]));
}

__global__ void edge_p_k(const int* __restrict__ dst, const float* __restrict__ ev,
                         const unsigned* __restrict__ mkey, float* __restrict__ p,
                         float* __restrict__ s, int E4) {
  int i = blockIdx.x * blockDim.x + threadIdx.x;
  if (i >= E4) return;
  int d4 = dst[i >> 2] * 4 + (i & 3);
  float m = fdec(mkey[d4]);
  float pv = expf(ev[i] - m);
  p[i] = pv;
  atomicAdd(&s[d4], pv);
}

__global__ void edge_alpha_k(const int* __restrict__ dst, const float* __restrict__ s,
                             float* __restrict__ p, int E4) {
  int i = blockIdx.x * blockDim.x + threadIdx.x;
  if (i >= E4) return;
  float sv = s[dst[i >> 2] * 4 + (i & 3)];
  p[i] = p[i] / (sv > 0.f ? sv : 1.f);
}

// ---------- aggregation from bf16 feat ----------
__global__ __launch_bounds__(256) void agg_k(const ushortT* __restrict__ featb,
                                             const float* __restrict__ alpha,
                                             const int* __restrict__ row_ptr,
                                             const int* __restrict__ edge_ord,
                                             const int* __restrict__ src,
                                             float* __restrict__ acc) {
  int n = blockIdx.x;
  int start = row_ptr[n], end = row_ptr[n + 1];
  if (end == start) return;
  __shared__ int s_src[256];
  __shared__ float s_al[256][4];
  int t = threadIdx.x;
  float o0[8] = {}, o1[8] = {};
  for (int c = start; c < end; c += 256) {
    int m = min(256, end - c);
    if (t < m) {
      int eid = edge_ord[c + t];
      s_src[t] = src[eid];
#pragma unroll
      for (int h = 0; h < 4; h++) s_al[t][h] = alpha[eid * 4 + h];
    }
    __syncthreads();
    for (int i = 0; i < m; i++) {
      const unsigned* frow = (const unsigned*)(featb + (size_t)s_src[i] * HID);
      float a0 = s_al[i][0], a1 = s_al[i][1], a2 = s_al[i][2], a3 = s_al[i][3];
#pragma unroll
      for (int j = 0; j < 8; j++) {
        unsigned u = frow[j * 256 + t];
        float av = (j < 2) ? a0 : (j < 4) ? a1 : (j < 6) ? a2 : a3;
        o0[j] += av * b2f_lo(u);
        o1[j] += av * b2f_hi(u);
      }
    }
    __syncthreads();
  }
#pragma unroll
  for (int j = 0; j < 8; j++) {
    float2* p = (float2*)(acc + (size_t)n * HID + (size_t)(j * 256 + t) * 2);
    float2 v = *p;
    v.x += o0[j];
    v.y += o1[j];
    *p = v;
  }
}

// ---------- finalize layer1: hb = bf16(elu((acc + sum_r b1)/4)) ----------
__global__ __launch_bounds__(256) void finalize1_k(const float* __restrict__ acc,
                                                   const float* __restrict__ b1,
                                                   ushortT* __restrict__ hb, int total) {
  int i = blockIdx.x * 256 + threadIdx.x;
  if (i >= total) return;
  int col = i & (HID - 1);
  float bs = b1[col] + b1[HID + col] + b1[2 * HID + col] + b1[3 * HID + col];
  float v = (acc[i] + bs) * 0.25f;
  v = v > 0.f ? v : (expf(v) - 1.f);
  hb[i] = f2b(v);
}

// ---------- finalize layer2 + column mean ----------
__global__ __launch_bounds__(256) void finalize2_mean_k(const float* __restrict__ acc,
                                                        const ushortT* __restrict__ hb,
                                                        const float* __restrict__ b2,
                                                        float* __restrict__ gm, int Nn,
                                                        float invN) {
  int col = blockIdx.x * 256 + threadIdx.x;
  int r0 = blockIdx.y * 32;
  int r1 = min(r0 + 32, Nn);
  float bs = 0.25f * (b2[col] + b2[HID + col] + b2[2 * HID + col] + b2[3 * HID + col]);
  float p = 0.f;
  for (int r = r0; r < r1; r++) {
    size_t i = (size_t)r * HID + col;
    p += acc[i] * 0.25f + b2f1(hb[i]) + bs;
  }
  atomicAdd(&gm[col], p * invN);
}

// ---------- readout MLP ----------
__global__ void initvec_k(float* __restrict__ out, const float* __restrict__ b, int n) {
  int i = blockIdx.x * blockDim.x + threadIdx.x;
  if (i < n) out[i] = b[i];
}

__global__ __launch_bounds__(256) void matvec_k(const float* __restrict__ v,
                                                const float* __restrict__ W,
                                                float* __restrict__ out, int K, int Nout,
                                                int kchunk) {
  int j = blockIdx.x * 256 + threadIdx.x;
  if (j >= Nout) return;
  int k0 = blockIdx.y * kchunk;
  int k1 = min(k0 + kchunk, K);
  float p = 0.f;
  for (int k = k0; k < k1; k++) p += v[k] * W[(size_t)k * Nout + j];
  atomicAdd(&out[j], p);
}

__global__ __launch_bounds__(256) void final_k(const float* __restrict__ hc,
                                               const float* __restrict__ Wc2,
                                               const float* __restrict__ bc2,
                                               float* __restrict__ out) {
  __shared__ float red[256];
  int t = threadIdx.x;
  for (int c = 0; c < 3; c++) {
    float p = 0.f;
    for (int k = t; k < 1024; k += 256) {
      float v = hc[k];
      v = v > 0.f ? v : 0.f;
      p += v * Wc2[k * 3 + c];
    }
    red[t] = p;
    __syncthreads();
    for (int s = 128; s > 0; s >>= 1) {
      if (t < s) red[t] += red[t + s];
      __syncthreads();
    }
    if (t == 0) out[c] = red[0] + bc2[c];
    __syncthreads();
  }
}

// ================= host side =================
extern "C" void kernel_launch(void* const* d_in, const int* in_sizes, int n_in,
                              void* d_out, int out_size, void* d_ws, size_t ws_size,
                              hipStream_t stream) {
  const float* x_pre = (const float*)d_in[0];
  const float* x_hyp = (const float*)d_in[1];
  const float* x_comb = (const float*)d_in[2];
  const int* src_pre = (const int*)d_in[3];
  const int* dst_pre = (const int*)d_in[4];
  const int* src_hyp = (const int*)d_in[5];
  const int* dst_hyp = (const int*)d_in[6];
  const int* src_comb = (const int*)d_in[7];
  const int* dst_comb = (const int*)d_in[8];
  const float* W1 = (const float*)d_in[9];
  const float* al1 = (const float*)d_in[10];
  const float* ar1 = (const float*)d_in[11];
  const float* b1 = (const float*)d_in[12];
  const float* res1 = (const float*)d_in[13];
  const float* W2 = (const float*)d_in[14];
  const float* al2 = (const float*)d_in[15];
  const float* ar2 = (const float*)d_in[16];
  const float* b2 = (const float*)d_in[17];
  const float* Wp = (const float*)d_in[18];
  const float* bp = (const float*)d_in[19];
  const float* Wc1 = (const float*)d_in[20];
  const float* bc1 = (const float*)d_in[21];
  const float* Wc2 = (const float*)d_in[22];
  const float* bc2 = (const float*)d_in[23];
  float* out = (float*)d_out;

  char* w = (char*)d_ws;
  size_t off = 0;
  auto alloc = [&](size_t bytes) -> void* {
    void* p = w + off;
    off = (off + bytes + 255) & ~(size_t)255;
    return p;
  };
  float* acc = (float*)alloc((size_t)NMAX * HID * 4);
  ushortT* hb = (ushortT*)alloc((size_t)NMAX * HID * 2);
  ushortT* featb = (ushortT*)alloc((size_t)NMAX * HID * 2);
  ushortT* xb = (ushortT*)alloc((size_t)NMAX * 1024 * 2);
  ushortT* Wt = (ushortT*)alloc((size_t)4096 * 4096 * 2);
  float* el = (float*)alloc(NMAX * 4 * 4);
  float* er = (float*)alloc(NMAX * 4 * 4);
  float* evals = (float*)alloc(EMAX * 4 * 4);
  float* alpha = (float*)alloc(EMAX * 4 * 4);
  unsigned* mkey = (unsigned*)alloc(NMAX * 4 * 4);
  float* sbuf = (float*)alloc(NMAX * 4 * 4);
  int* row_ptr = (int*)alloc(RREL * (NMAX + 1) * 4);
  int* edge_ord = (int*)alloc(RREL * EMAX * 4);
  int* counts = (int*)alloc(NMAX * 4);
  float* gm = (float*)alloc(3 * HID * 4);
  float* z = (float*)alloc(3072 * 4);
  float* hc = (float*)alloc(1024 * 4);

  hipMemsetAsync(gm, 0, 3 * HID * 4, stream);

  struct GDesc { const float* x; const int* src; const int* dst; int N; int E; };
  GDesc gs[3] = {{x_pre, src_pre, dst_pre, 1024, 8192},
                 {x_hyp, src_hyp, dst_hyp, 1024, 8192},
                 {x_comb, src_comb, dst_comb, 2048, 16384}};

  for (int g = 0; g < 3; g++) {
    const float* x = gs[g].x;
    int N = gs[g].N, E = gs[g].E;
    int E4 = E * 4;
    dim3 gemmGrid(HID / 128, N / 128);
    int eb = (E + 255) / 256;
    int eb4 = (E4 + 255) / 256;

    // CSR per relation (reused by both layers)
    for (int r = 0; r < RREL; r++) {
      const int* dstR = gs[g].dst + (size_t)r * E;
      int* rpR = row_ptr + r * (NMAX + 1);
      int* eoR = edge_ord + r * EMAX;
      hipMemsetAsync(counts, 0, N * 4, stream);
      count_k<<<eb, 256, 0, stream>>>(dstR, counts, E);
      scan_k<<<1, 256, 0, stream>>>(counts, rpR, N);
      hipMemsetAsync(counts, 0, N * 4, stream);
      scatter_k<<<eb, 256, 0, stream>>>(dstR, counts, rpR, eoR, E);
    }

    // x -> bf16
    f2b_k<<<(N * 1024 / 8 + 255) / 256, 256, 0, stream>>>(x, xb, N * 1024 / 8);

    for (int layer = 0; layer < 2; layer++) {
      int K = (layer == 0) ? 1024 : HID;
      const ushortT* Ab = (layer == 0) ? xb : hb;
      const float* Wl = (layer == 0) ? W1 : W2;
      const float* all = (layer == 0) ? al1 : al2;
      const float* arl = (layer == 0) ? ar1 : ar2;
      dim3 convGrid(4096 / 32, K / 32);
      hipMemsetAsync(acc, 0, (size_t)N * HID * 4, stream);
      for (int r = 0; r < RREL; r++) {
        const int* srcR = gs[g].src + (size_t)r * E;
        const int* dstR = gs[g].dst + (size_t)r * E;
        const int* rpR = row_ptr + r * (NMAX + 1);
        const int* eoR = edge_ord + r * EMAX;
        // feat = A @ W_r  (bf16 out)
        convt_k<<<convGrid, 256, 0, stream>>>(Wl + (size_t)r * K * HID, Wt, K);
        gemm_bt<<<gemmGrid, 256, 0, stream>>>(Ab, Wt, (float*)nullptr, featb, N, K, 2);
        if (layer == 0) {
          // acc += x @ res1_r  (fp32 accum)
          convt_k<<<convGrid, 256, 0, stream>>>(res1 + (size_t)r * 1024 * HID, Wt, 1024);
          gemm_bt<<<gemmGrid, 256, 0, stream>>>(xb, Wt, acc, (ushortT*)nullptr, N, 1024, 1);
        }
        el_er_k<<<N, 256, 0, stream>>>(featb, all + r * HID, arl + r * HID, el, er);
        edge_vals_k<<<eb4, 256, 0, stream>>>(srcR, dstR, el, er, evals, E4);
        hipMemsetAsync(mkey, 0, N * 4 * 4, stream);
        edge_max_k<<<eb4, 256, 0, stream>>>(dstR, evals, mkey, E4);
        hipMemsetAsync(sbuf, 0, N * 4 * 4, stream);
        edge_p_k<<<eb4, 256, 0, stream>>>(dstR, evals, mkey, alpha, sbuf, E4);
        edge_alpha_k<<<eb4, 256, 0, stream>>>(dstR, sbuf, alpha, E4);
        agg_k<<<N, 256, 0, stream>>>(featb, alpha, rpR, eoR, srcR, acc);
      }
      if (layer == 0) {
        finalize1_k<<<N * (HID / 256), 256, 0, stream>>>(acc, b1, hb, N * HID);
      } else {
        dim3 fg(HID / 256, (N + 31) / 32);
        finalize2_mean_k<<<fg, 256, 0, stream>>>(acc, hb, b2, gm + g * HID, N, 1.0f / N);
      }
    }
  }

  // readout MLP (fp32)
  initvec_k<<<12, 256, 0, stream>>>(z, bp, 3072);
  {
    dim3 mg(3072 / 256, 48);
    matvec_k<<<mg, 256, 0, stream>>>(gm, Wp, z, 12288, 3072, 256);
  }
  initvec_k<<<4, 256, 0, stream>>>(hc, bc1, 1024);
  {
    dim3 mg(1024 / 256, 24);
    matvec_k<<<mg, 256, 0, stream>>>(z, Wc1, hc, 3072, 1024, 128);
  }
  final_k<<<1, 256, 0, stream>>>(hc, Wc2, bc2, out);
}